// Round 2
// 509.066 us; speedup vs baseline: 1.0374x; 1.0374x over previous
//
#include <hip/hip_runtime.h>
#include <math.h>

#define N_NODES 8192
#define NFEAT 256
#define NHID 64
#define NHEADS 4
#define NCLASS 121
#define NCPAD 128
#define CAP 256
#define LRALPHA 0.2f

typedef float f32x4 __attribute__((ext_vector_type(4)));

// ---------------------------------------------------------------------------
// K1: build per-row neighbor lists from dense adjacency (one block per row).
// adj is 0.0/1.0 float; ~82 edges/row expected, CAP=256 is ~19 sigma headroom.
// Nontemporal: adj is read-once 256 MB, keep it out of L2.
// ---------------------------------------------------------------------------
__global__ __launch_bounds__(256) void build_csr(const float* __restrict__ adj,
                                                 int* __restrict__ nbr,
                                                 int* __restrict__ deg) {
    int row = blockIdx.x;
    __shared__ int cnt;
    if (threadIdx.x == 0) cnt = 0;
    __syncthreads();
    const f32x4* arow = (const f32x4*)(adj + (size_t)row * N_NODES);
    for (int j4 = threadIdx.x; j4 < N_NODES / 4; j4 += 256) {
        f32x4 v = __builtin_nontemporal_load(&arow[j4]);
        if (v.x > 0.f) { int s = atomicAdd(&cnt, 1); if (s < CAP) nbr[row * CAP + s] = j4 * 4 + 0; }
        if (v.y > 0.f) { int s = atomicAdd(&cnt, 1); if (s < CAP) nbr[row * CAP + s] = j4 * 4 + 1; }
        if (v.z > 0.f) { int s = atomicAdd(&cnt, 1); if (s < CAP) nbr[row * CAP + s] = j4 * 4 + 2; }
        if (v.w > 0.f) { int s = atomicAdd(&cnt, 1); if (s < CAP) nbr[row * CAP + s] = j4 * 4 + 3; }
    }
    __syncthreads();
    if (threadIdx.x == 0) deg[row] = cnt < CAP ? cnt : CAP;
}

// ---------------------------------------------------------------------------
// K2: pad W_out [256,121] -> [256,128] (zeros) and a_out [242] -> [256].
// ---------------------------------------------------------------------------
__global__ __launch_bounds__(256) void pad_params(const float* __restrict__ Wout,
                                                  const float* __restrict__ aout,
                                                  float* __restrict__ Wpad,
                                                  float* __restrict__ apad) {
    int idx = blockIdx.x * 256 + threadIdx.x;
    if (idx < 256 * NCPAD) {
        int k = idx >> 7, c = idx & 127;
        Wpad[idx] = (c < NCLASS) ? Wout[k * NCLASS + c] : 0.f;
    }
    if (idx < 256) {
        int c = idx & 127;
        float v = 0.f;
        if (c < NCLASS) v = (idx < 128) ? aout[c] : aout[NCLASS + c];
        apad[idx] = v;
    }
}

// ---------------------------------------------------------------------------
// K3: layer-1 GEMM. Output HEAD-MAJOR: Wh1h[h][i][d] (2 MB per head)
// so the layer-1 aggregation gather working set fits a single XCD L2.
// ---------------------------------------------------------------------------
__global__ __launch_bounds__(256) void gemm1(const float* __restrict__ x,
                                             const float* __restrict__ Ws,
                                             float* __restrict__ Wh1h) {
    int h = blockIdx.y;
    int r0 = blockIdx.x * 64;
    __shared__ float xs[64][260];
    for (int t = threadIdx.x; t < 64 * 64; t += 256) {
        int r = t >> 6, c4 = t & 63;
        *(float4*)&xs[r][c4 * 4] = *(const float4*)(x + (size_t)(r0 + r) * NFEAT + c4 * 4);
    }
    __syncthreads();
    int d = threadIdx.x & 63;
    int rb = (threadIdx.x >> 6) * 16;
    const float* W = Ws + (size_t)h * NFEAT * NHID + d;  // W[k][d]
    float acc[16] = {};
    for (int k4 = 0; k4 < NFEAT; k4 += 4) {
        float b0 = W[(k4 + 0) * NHID];
        float b1 = W[(k4 + 1) * NHID];
        float b2 = W[(k4 + 2) * NHID];
        float b3 = W[(k4 + 3) * NHID];
#pragma unroll
        for (int r = 0; r < 16; r++) {
            float4 a = *(const float4*)&xs[rb + r][k4];
            acc[r] += a.x * b0 + a.y * b1 + a.z * b2 + a.w * b3;
        }
    }
#pragma unroll
    for (int r = 0; r < 16; r++)
        Wh1h[((size_t)h * N_NODES + (r0 + rb + r)) * NHID + d] = acc[r];
}

// ---------------------------------------------------------------------------
// K4: layer-1 attention coefficients (head-major Wh1h).
// ---------------------------------------------------------------------------
__global__ __launch_bounds__(256) void attn_coef1(const float* __restrict__ Wh1h,
                                                  const float* __restrict__ a_heads,
                                                  float* __restrict__ fs1,
                                                  float* __restrict__ fd1) {
    int i = blockIdx.x;
    int h = threadIdx.x >> 6, lane = threadIdx.x & 63;
    float wh = Wh1h[((size_t)h * N_NODES + i) * NHID + lane];
    float s = wh * a_heads[h * 2 * NHID + lane];
    float dd = wh * a_heads[h * 2 * NHID + NHID + lane];
#pragma unroll
    for (int o = 32; o > 0; o >>= 1) { s += __shfl_down(s, o); dd += __shfl_down(dd, o); }
    if (lane == 0) { fs1[h * N_NODES + i] = s; fd1[h * N_NODES + i] = dd; }
}

// ---------------------------------------------------------------------------
// K5: layer-1 sparse softmax + aggregate + ELU.
// Wave = (node, head). XCD-pinned: blockIdx%8 -> XCD (round-robin dispatch),
// head h only on XCD slots {2h, 2h+1}, so each XCD gathers from a 2 MB
// head-slice of Wh1h that stays L2-resident (4 MB/XCD).
//   b&7      : XCD slot -> h = slot>>1, sub = slot&1
//   g        = (b>>3)*2 + sub  in [0,2048)
//   node i   = g*4 + wave      (4 waves/block)
// ---------------------------------------------------------------------------
__global__ __launch_bounds__(256) void attn_agg1(const int* __restrict__ nbr,
                                                 const int* __restrict__ deg,
                                                 const float* __restrict__ Wh1h,
                                                 const float* __restrict__ fs1,
                                                 const float* __restrict__ fd1,
                                                 float* __restrict__ hcat) {
    int b = blockIdx.x;
    int w = threadIdx.x >> 6, lane = threadIdx.x & 63;
    int slot = b & 7;
    int h = slot >> 1;
    int g = ((b >> 3) << 1) | (slot & 1);
    int i = (g << 2) | w;
    __shared__ float ebuf[4][CAP];
    __shared__ int nbrs[4][CAP];
    int dg = deg[i];
    for (int t = lane; t < dg; t += 64)
        nbrs[w][t] = __builtin_nontemporal_load(&nbr[i * CAP + t]);
    float fsi = fs1[h * N_NODES + i];
    const float* fdh = fd1 + h * N_NODES;
    float m = -3.4e38f;
    for (int t = lane; t < dg; t += 64) {   // same t-set this lane wrote above
        float e = fsi + fdh[nbrs[w][t]];
        e = e > 0.f ? e : LRALPHA * e;
        ebuf[w][t] = e;
        m = fmaxf(m, e);
    }
#pragma unroll
    for (int o = 32; o > 0; o >>= 1) m = fmaxf(m, __shfl_xor(m, o));
    float s = 0.f;
    for (int t = lane; t < dg; t += 64) {
        float p = __expf(ebuf[w][t] - m);
        ebuf[w][t] = p;
        s += p;
    }
#pragma unroll
    for (int o = 32; o > 0; o >>= 1) s += __shfl_xor(s, o);
    __syncthreads();  // cross-lane ebuf/nbrs visibility for the gather loop
    float acc = 0.f;
    const float* wcol = Wh1h + (size_t)h * N_NODES * NHID + lane;
#pragma unroll 4
    for (int t = 0; t < dg; t++) {
        acc += ebuf[w][t] * wcol[(size_t)nbrs[w][t] * NHID];
    }
    acc /= s;
    float r = acc > 0.f ? acc : expm1f(acc);  // ELU alpha=1
    __builtin_nontemporal_store(r, &hcat[(size_t)i * (NHEADS * NHID) + h * NHID + lane]);
}

// ---------------------------------------------------------------------------
// K6: layer-2 GEMM. Output in COLUMN-HALF-MAJOR layout: Wh2h[half][i][64]
// (2 MB per half) for the layer-2 aggregation's XCD-local gather.
// ---------------------------------------------------------------------------
__global__ __launch_bounds__(256) void gemm2(const float* __restrict__ hcat,
                                             const float* __restrict__ Wpad,
                                             float* __restrict__ Wh2h) {
    int r0 = blockIdx.x * 64;
    __shared__ float xs[64][260];
    for (int t = threadIdx.x; t < 64 * 64; t += 256) {
        int r = t >> 6, c4 = t & 63;
        *(float4*)&xs[r][c4 * 4] = *(const float4*)(hcat + (size_t)(r0 + r) * 256 + c4 * 4);
    }
    __syncthreads();
    int c0 = (threadIdx.x & 63) * 2;
    int rb = (threadIdx.x >> 6) * 16;
    int half = c0 >> 6, cc = c0 & 63;
    float acc0[16] = {}, acc1[16] = {};
    for (int k4 = 0; k4 < 256; k4 += 4) {
        float2 b0 = *(const float2*)&Wpad[(k4 + 0) * NCPAD + c0];
        float2 b1 = *(const float2*)&Wpad[(k4 + 1) * NCPAD + c0];
        float2 b2 = *(const float2*)&Wpad[(k4 + 2) * NCPAD + c0];
        float2 b3 = *(const float2*)&Wpad[(k4 + 3) * NCPAD + c0];
#pragma unroll
        for (int r = 0; r < 16; r++) {
            float4 a = *(const float4*)&xs[rb + r][k4];
            acc0[r] += a.x * b0.x + a.y * b1.x + a.z * b2.x + a.w * b3.x;
            acc1[r] += a.x * b0.y + a.y * b1.y + a.z * b2.y + a.w * b3.y;
        }
    }
#pragma unroll
    for (int r = 0; r < 16; r++) {
        float2 v = make_float2(acc0[r], acc1[r]);
        *(float2*)&Wh2h[((size_t)half * N_NODES + (r0 + rb + r)) * 64 + cc] = v;
    }
}

// ---------------------------------------------------------------------------
// K7: layer-2 attention coefficients (half-major Wh2h).
// ---------------------------------------------------------------------------
__global__ __launch_bounds__(256) void attn_coef2(const float* __restrict__ Wh2h,
                                                  const float* __restrict__ apad,
                                                  float* __restrict__ fs2,
                                                  float* __restrict__ fd2) {
    int i = blockIdx.x * 4 + (threadIdx.x >> 6);
    int lane = threadIdx.x & 63;
    float w0 = Wh2h[(size_t)i * 64 + lane];                    // half 0
    float w1 = Wh2h[((size_t)N_NODES + i) * 64 + lane];        // half 1
    float s = w0 * apad[lane] + w1 * apad[64 + lane];
    float dd = w0 * apad[128 + lane] + w1 * apad[192 + lane];
#pragma unroll
    for (int o = 32; o > 0; o >>= 1) { s += __shfl_down(s, o); dd += __shfl_down(dd, o); }
    if (lane == 0) { fs2[i] = s; fd2[i] = dd; }
}

// ---------------------------------------------------------------------------
// K8: layer-2 sparse softmax + aggregate. Wave = (node, class-half).
// Half hf pinned to XCD slots {4hf..4hf+3}; each XCD's gather working set is
// its half's 2 MB slice of Wh2h (L2-resident). Softmax recomputed per half
// (identical FP sequence in both halves).
//   b&7 : slot -> hf = slot>>2, sub = slot&3
//   g   = (b>>3)*4 + sub in [0,2048); node i = g*4 + wave
// ---------------------------------------------------------------------------
__global__ __launch_bounds__(256) void attn_agg2(const int* __restrict__ nbr,
                                                 const int* __restrict__ deg,
                                                 const float* __restrict__ Wh2h,
                                                 const float* __restrict__ fs2,
                                                 const float* __restrict__ fd2,
                                                 float* __restrict__ out) {
    int b = blockIdx.x;
    int w = threadIdx.x >> 6, lane = threadIdx.x & 63;
    int slot = b & 7;
    int hf = slot >> 2;
    int g = ((b >> 3) << 2) | (slot & 3);
    int i = (g << 2) | w;
    __shared__ float ebuf[4][CAP];
    __shared__ int nbrs[4][CAP];
    int dg = deg[i];
    for (int t = lane; t < dg; t += 64)
        nbrs[w][t] = __builtin_nontemporal_load(&nbr[i * CAP + t]);
    float fsi = fs2[i];
    float m = -3.4e38f;
    for (int t = lane; t < dg; t += 64) {
        float e = fsi + fd2[nbrs[w][t]];
        e = e > 0.f ? e : LRALPHA * e;
        ebuf[w][t] = e;
        m = fmaxf(m, e);
    }
#pragma unroll
    for (int o = 32; o > 0; o >>= 1) m = fmaxf(m, __shfl_xor(m, o));
    float s = 0.f;
    for (int t = lane; t < dg; t += 64) {
        float p = __expf(ebuf[w][t] - m);
        ebuf[w][t] = p;
        s += p;
    }
#pragma unroll
    for (int o = 32; o > 0; o >>= 1) s += __shfl_xor(s, o);
    __syncthreads();
    float acc = 0.f;
    const float* wcol = Wh2h + (size_t)hf * N_NODES * 64 + lane;
#pragma unroll 4
    for (int t = 0; t < dg; t++) {
        acc += ebuf[w][t] * wcol[(size_t)nbrs[w][t] * 64];
    }
    int c = hf * 64 + lane;
    if (c < NCLASS)
        __builtin_nontemporal_store(acc / s, &out[(size_t)i * NCLASS + c]);
}

// ---------------------------------------------------------------------------

extern "C" void kernel_launch(void* const* d_in, const int* in_sizes, int n_in,
                              void* d_out, int out_size, void* d_ws, size_t ws_size,
                              hipStream_t stream) {
    const float* x       = (const float*)d_in[0];  // [8192,256]
    const float* adj     = (const float*)d_in[1];  // [8192,8192]
    const float* Ws      = (const float*)d_in[2];  // [4,256,64]
    const float* a_heads = (const float*)d_in[3];  // [4,128]
    const float* Wout    = (const float*)d_in[4];  // [256,121]
    const float* aout    = (const float*)d_in[5];  // [242]
    float* out = (float*)d_out;                    // [8192,121]

    char* ws = (char*)d_ws;
    size_t off = 0;
    auto alloc = [&](size_t bytes) { void* p = ws + off; off = (off + bytes + 255) & ~(size_t)255; return p; };
    int*   nbr  = (int*)  alloc((size_t)N_NODES * CAP * 4);           // 8 MB
    int*   deg  = (int*)  alloc((size_t)N_NODES * 4);                 // 32 KB
    float* Wh1h = (float*)alloc((size_t)NHEADS * N_NODES * NHID * 4); // 8 MB, head-major
    float* fs1  = (float*)alloc((size_t)NHEADS * N_NODES * 4);
    float* fd1  = (float*)alloc((size_t)NHEADS * N_NODES * 4);
    float* hcat = (float*)alloc((size_t)N_NODES * NHEADS * NHID * 4); // 8 MB
    float* Wh2h = (float*)alloc((size_t)2 * N_NODES * 64 * 4);        // 4 MB, half-major
    float* fs2  = (float*)alloc((size_t)N_NODES * 4);
    float* fd2  = (float*)alloc((size_t)N_NODES * 4);
    float* Wpad = (float*)alloc((size_t)256 * NCPAD * 4);
    float* apad = (float*)alloc((size_t)256 * 4);

    build_csr<<<N_NODES, 256, 0, stream>>>(adj, nbr, deg);
    pad_params<<<128, 256, 0, stream>>>(Wout, aout, Wpad, apad);
    gemm1<<<dim3(N_NODES / 64, NHEADS), 256, 0, stream>>>(x, Ws, Wh1h);
    attn_coef1<<<N_NODES, 256, 0, stream>>>(Wh1h, a_heads, fs1, fd1);
    attn_agg1<<<N_NODES, 256, 0, stream>>>(nbr, deg, Wh1h, fs1, fd1, hcat);
    gemm2<<<N_NODES / 64, 256, 0, stream>>>(hcat, Wpad, Wh2h);
    attn_coef2<<<N_NODES / 4, 256, 0, stream>>>(Wh2h, apad, fs2, fd2);
    attn_agg2<<<N_NODES / 2, 256, 0, stream>>>(nbr, deg, Wh2h, fs2, fd2, out);
}

// Round 3
// 485.192 us; speedup vs baseline: 1.0885x; 1.0492x over previous
//
#include <hip/hip_runtime.h>
#include <math.h>

#define N_NODES 8192
#define NFEAT 256
#define NHID 64
#define NHEADS 4
#define NCLASS 121
#define NCPAD 128
#define CAP 256
#define LRALPHA 0.2f

typedef float f32x4 __attribute__((ext_vector_type(4)));

__device__ __forceinline__ float lrelu(float x) { return x > 0.f ? x : LRALPHA * x; }
__device__ __forceinline__ f32x4 splat4(float v) { f32x4 r = {v, v, v, v}; return r; }

// ---------------------------------------------------------------------------
// K1: build per-row neighbor lists from dense adjacency (one block per row).
// adj is 0.0/1.0 float; ~82 edges/row expected, CAP=256 is ~19 sigma headroom.
// Nontemporal: adj is read-once 256 MB, keep it out of L2.
// ---------------------------------------------------------------------------
__global__ __launch_bounds__(256) void build_csr(const float* __restrict__ adj,
                                                 int* __restrict__ nbr,
                                                 int* __restrict__ deg) {
    int row = blockIdx.x;
    __shared__ int cnt;
    if (threadIdx.x == 0) cnt = 0;
    __syncthreads();
    const f32x4* arow = (const f32x4*)(adj + (size_t)row * N_NODES);
    for (int j4 = threadIdx.x; j4 < N_NODES / 4; j4 += 256) {
        f32x4 v = __builtin_nontemporal_load(&arow[j4]);
        if (v.x > 0.f) { int s = atomicAdd(&cnt, 1); if (s < CAP) nbr[row * CAP + s] = j4 * 4 + 0; }
        if (v.y > 0.f) { int s = atomicAdd(&cnt, 1); if (s < CAP) nbr[row * CAP + s] = j4 * 4 + 1; }
        if (v.z > 0.f) { int s = atomicAdd(&cnt, 1); if (s < CAP) nbr[row * CAP + s] = j4 * 4 + 2; }
        if (v.w > 0.f) { int s = atomicAdd(&cnt, 1); if (s < CAP) nbr[row * CAP + s] = j4 * 4 + 3; }
    }
    __syncthreads();
    if (threadIdx.x == 0) deg[row] = cnt < CAP ? cnt : CAP;
}

// ---------------------------------------------------------------------------
// K2: pad W_out [256,121] -> [256,128] (zeros) and a_out [242] -> [256].
// ---------------------------------------------------------------------------
__global__ __launch_bounds__(256) void pad_params(const float* __restrict__ Wout,
                                                  const float* __restrict__ aout,
                                                  float* __restrict__ Wpad,
                                                  float* __restrict__ apad) {
    int idx = blockIdx.x * 256 + threadIdx.x;
    if (idx < 256 * NCPAD) {
        int k = idx >> 7, c = idx & 127;
        Wpad[idx] = (c < NCLASS) ? Wout[k * NCLASS + c] : 0.f;
    }
    if (idx < 256) {
        int c = idx & 127;
        float v = 0.f;
        if (c < NCLASS) v = (idx < 128) ? aout[c] : aout[NCLASS + c];
        apad[idx] = v;
    }
}

// ---------------------------------------------------------------------------
// K3: layer-1 GEMM. Output INTERLEAVED: Wh1[i][h*64+d] (full 1 KB node rows)
// so the aggregation gathers one contiguous row per edge for all 4 heads.
// ---------------------------------------------------------------------------
__global__ __launch_bounds__(256) void gemm1(const float* __restrict__ x,
                                             const float* __restrict__ Ws,
                                             float* __restrict__ Wh1) {
    int h = blockIdx.y;
    int r0 = blockIdx.x * 64;
    __shared__ float xs[64][260];
    for (int t = threadIdx.x; t < 64 * 64; t += 256) {
        int r = t >> 6, c4 = t & 63;
        *(float4*)&xs[r][c4 * 4] = *(const float4*)(x + (size_t)(r0 + r) * NFEAT + c4 * 4);
    }
    __syncthreads();
    int d = threadIdx.x & 63;
    int rb = (threadIdx.x >> 6) * 16;
    const float* W = Ws + (size_t)h * NFEAT * NHID + d;  // W[k][d]
    float acc[16] = {};
    for (int k4 = 0; k4 < NFEAT; k4 += 4) {
        float b0 = W[(k4 + 0) * NHID];
        float b1 = W[(k4 + 1) * NHID];
        float b2 = W[(k4 + 2) * NHID];
        float b3 = W[(k4 + 3) * NHID];
#pragma unroll
        for (int r = 0; r < 16; r++) {
            float4 a = *(const float4*)&xs[rb + r][k4];
            acc[r] += a.x * b0 + a.y * b1 + a.z * b2 + a.w * b3;
        }
    }
#pragma unroll
    for (int r = 0; r < 16; r++)
        Wh1[(size_t)(r0 + rb + r) * (NHEADS * NHID) + h * NHID + d] = acc[r];
}

// ---------------------------------------------------------------------------
// K4: layer-1 attention coefficients. Block = node, wave = head.
// Outputs NODE-MAJOR float4: fs1t[i][h], fd1t[i][h] — one 16 B load gives all
// 4 heads' coefficients in the aggregation.
// ---------------------------------------------------------------------------
__global__ __launch_bounds__(256) void attn_coef1(const float* __restrict__ Wh1,
                                                  const float* __restrict__ a_heads,
                                                  float* __restrict__ fs1t,
                                                  float* __restrict__ fd1t) {
    int i = blockIdx.x;
    int h = threadIdx.x >> 6, lane = threadIdx.x & 63;
    float wh = Wh1[(size_t)i * (NHEADS * NHID) + h * NHID + lane];
    float s = wh * a_heads[h * 2 * NHID + lane];
    float dd = wh * a_heads[h * 2 * NHID + NHID + lane];
#pragma unroll
    for (int o = 32; o > 0; o >>= 1) { s += __shfl_down(s, o); dd += __shfl_down(dd, o); }
    if (lane == 0) { fs1t[i * 4 + h] = s; fd1t[i * 4 + h] = dd; }
}

// ---------------------------------------------------------------------------
// K5: layer-1 sparse softmax (4 heads packed) + aggregate + ELU.
// ONE WAVE PER NODE: per edge, a single global_load_dwordx4 fetches the full
// 1 KB row Wh1[j][0:256] (lane l -> head l>>4, dims 4l..4l+3), serving all
// 4 heads at once. Softmax computed packed float4 in registers.
// ---------------------------------------------------------------------------
__global__ __launch_bounds__(256) void attn_agg1(const int* __restrict__ nbr,
                                                 const int* __restrict__ deg,
                                                 const float* __restrict__ Wh1,
                                                 const float* __restrict__ fs1t,
                                                 const float* __restrict__ fd1t,
                                                 float* __restrict__ hcat) {
    int w = threadIdx.x >> 6, lane = threadIdx.x & 63;
    int i = blockIdx.x * 4 + w;
    __shared__ int nbrs[4][CAP];
    __shared__ float pbuf[4][CAP][4];   // per-edge per-head softmax numerators
    int dg = deg[i];
    for (int t = lane; t < dg; t += 64)
        nbrs[w][t] = nbr[i * CAP + t];
    f32x4 fsi = *(const f32x4*)(fs1t + (size_t)i * 4);
    f32x4 e[4];
    f32x4 m4 = {-3.4e38f, -3.4e38f, -3.4e38f, -3.4e38f};
#pragma unroll
    for (int k = 0; k < 4; k++) {
        int t = lane + (k << 6);
        if (t < dg) {
            int j = nbrs[w][t];                         // own lane's writes
            f32x4 fdj = *(const f32x4*)(fd1t + (size_t)j * 4);
            f32x4 ev;
            ev.x = lrelu(fsi.x + fdj.x);
            ev.y = lrelu(fsi.y + fdj.y);
            ev.z = lrelu(fsi.z + fdj.z);
            ev.w = lrelu(fsi.w + fdj.w);
            e[k] = ev;
            m4.x = fmaxf(m4.x, ev.x); m4.y = fmaxf(m4.y, ev.y);
            m4.z = fmaxf(m4.z, ev.z); m4.w = fmaxf(m4.w, ev.w);
        }
    }
#pragma unroll
    for (int o = 32; o > 0; o >>= 1) {
        m4.x = fmaxf(m4.x, __shfl_xor(m4.x, o));
        m4.y = fmaxf(m4.y, __shfl_xor(m4.y, o));
        m4.z = fmaxf(m4.z, __shfl_xor(m4.z, o));
        m4.w = fmaxf(m4.w, __shfl_xor(m4.w, o));
    }
    f32x4 s4 = {0.f, 0.f, 0.f, 0.f};
#pragma unroll
    for (int k = 0; k < 4; k++) {
        int t = lane + (k << 6);
        if (t < dg) {
            f32x4 p;
            p.x = __expf(e[k].x - m4.x);
            p.y = __expf(e[k].y - m4.y);
            p.z = __expf(e[k].z - m4.z);
            p.w = __expf(e[k].w - m4.w);
            *(f32x4*)&pbuf[w][t][0] = p;
            s4 += p;
        }
    }
#pragma unroll
    for (int o = 32; o > 0; o >>= 1) {
        s4.x += __shfl_xor(s4.x, o);
        s4.y += __shfl_xor(s4.y, o);
        s4.z += __shfl_xor(s4.z, o);
        s4.w += __shfl_xor(s4.w, o);
    }
    __syncthreads();  // nbrs + pbuf cross-lane visibility
    int hl = lane >> 4;
    const float* wrow = Wh1 + 4 * lane;
    f32x4 acc = {0.f, 0.f, 0.f, 0.f};
#pragma unroll 4
    for (int t = 0; t < dg; t++) {
        int j = nbrs[w][t];
        float p = pbuf[w][t][hl];
        f32x4 wv = *(const f32x4*)(wrow + (size_t)j * (NHEADS * NHID));
        acc += wv * splat4(p);
    }
    float sh = hl == 0 ? s4.x : hl == 1 ? s4.y : hl == 2 ? s4.z : s4.w;
    acc.x /= sh; acc.y /= sh; acc.z /= sh; acc.w /= sh;
    acc.x = acc.x > 0.f ? acc.x : expm1f(acc.x);
    acc.y = acc.y > 0.f ? acc.y : expm1f(acc.y);
    acc.z = acc.z > 0.f ? acc.z : expm1f(acc.z);
    acc.w = acc.w > 0.f ? acc.w : expm1f(acc.w);
    *(f32x4*)(hcat + (size_t)i * (NHEADS * NHID) + 4 * lane) = acc;
}

// ---------------------------------------------------------------------------
// K6: layer-2 GEMM. Row-major Wh2[i][128] (full 512 B node rows).
// ---------------------------------------------------------------------------
__global__ __launch_bounds__(256) void gemm2(const float* __restrict__ hcat,
                                             const float* __restrict__ Wpad,
                                             float* __restrict__ Wh2) {
    int r0 = blockIdx.x * 64;
    __shared__ float xs[64][260];
    for (int t = threadIdx.x; t < 64 * 64; t += 256) {
        int r = t >> 6, c4 = t & 63;
        *(float4*)&xs[r][c4 * 4] = *(const float4*)(hcat + (size_t)(r0 + r) * 256 + c4 * 4);
    }
    __syncthreads();
    int c0 = (threadIdx.x & 63) * 2;
    int rb = (threadIdx.x >> 6) * 16;
    float acc0[16] = {}, acc1[16] = {};
    for (int k4 = 0; k4 < 256; k4 += 4) {
        float2 b0 = *(const float2*)&Wpad[(k4 + 0) * NCPAD + c0];
        float2 b1 = *(const float2*)&Wpad[(k4 + 1) * NCPAD + c0];
        float2 b2 = *(const float2*)&Wpad[(k4 + 2) * NCPAD + c0];
        float2 b3 = *(const float2*)&Wpad[(k4 + 3) * NCPAD + c0];
#pragma unroll
        for (int r = 0; r < 16; r++) {
            float4 a = *(const float4*)&xs[rb + r][k4];
            acc0[r] += a.x * b0.x + a.y * b1.x + a.z * b2.x + a.w * b3.x;
            acc1[r] += a.x * b0.y + a.y * b1.y + a.z * b2.y + a.w * b3.y;
        }
    }
#pragma unroll
    for (int r = 0; r < 16; r++) {
        float2 v = make_float2(acc0[r], acc1[r]);
        *(float2*)&Wh2[(size_t)(r0 + rb + r) * NCPAD + c0] = v;
    }
}

// ---------------------------------------------------------------------------
// K7: layer-2 attention coefficients. Wave per node (4 nodes/block).
// ---------------------------------------------------------------------------
__global__ __launch_bounds__(256) void attn_coef2(const float* __restrict__ Wh2,
                                                  const float* __restrict__ apad,
                                                  float* __restrict__ fs2,
                                                  float* __restrict__ fd2) {
    int i = blockIdx.x * 4 + (threadIdx.x >> 6);
    int lane = threadIdx.x & 63;
    float w0 = Wh2[(size_t)i * NCPAD + lane];
    float w1 = Wh2[(size_t)i * NCPAD + 64 + lane];
    float s = w0 * apad[lane] + w1 * apad[64 + lane];
    float dd = w0 * apad[128 + lane] + w1 * apad[192 + lane];
#pragma unroll
    for (int o = 32; o > 0; o >>= 1) { s += __shfl_down(s, o); dd += __shfl_down(dd, o); }
    if (lane == 0) { fs2[i] = s; fd2[i] = dd; }
}

// ---------------------------------------------------------------------------
// K8: layer-2 sparse softmax + aggregate. ONE WAVE PER NODE; gather processes
// 2 edges/iteration (lane half eg=l>>5 takes edge t+eg, float4 over 128 cols),
// halves combined by shfl_xor(32) at the end.
// ---------------------------------------------------------------------------
__global__ __launch_bounds__(256) void attn_agg2(const int* __restrict__ nbr,
                                                 const int* __restrict__ deg,
                                                 const float* __restrict__ Wh2,
                                                 const float* __restrict__ fs2,
                                                 const float* __restrict__ fd2,
                                                 float* __restrict__ out) {
    int w = threadIdx.x >> 6, lane = threadIdx.x & 63;
    int i = blockIdx.x * 4 + w;
    __shared__ int nbrs[4][CAP];
    __shared__ float pbuf[4][CAP];
    int dg = deg[i];
    for (int t = lane; t < dg; t += 64)
        nbrs[w][t] = nbr[i * CAP + t];
    float fsi = fs2[i];
    float e[4];
    float m = -3.4e38f;
#pragma unroll
    for (int k = 0; k < 4; k++) {
        int t = lane + (k << 6);
        if (t < dg) {
            float ev = lrelu(fsi + fd2[nbrs[w][t]]);
            e[k] = ev;
            m = fmaxf(m, ev);
        }
    }
#pragma unroll
    for (int o = 32; o > 0; o >>= 1) m = fmaxf(m, __shfl_xor(m, o));
    float s = 0.f;
#pragma unroll
    for (int k = 0; k < 4; k++) {
        int t = lane + (k << 6);
        if (t < dg) {
            float p = __expf(e[k] - m);
            pbuf[w][t] = p;
            s += p;
        }
    }
#pragma unroll
    for (int o = 32; o > 0; o >>= 1) s += __shfl_xor(s, o);
    __syncthreads();  // nbrs + pbuf cross-lane visibility
    int eg = lane >> 5, c = lane & 31;
    const float* wrow = Wh2 + 4 * c;
    f32x4 acc = {0.f, 0.f, 0.f, 0.f};
    for (int tt = 0; tt < dg; tt += 2) {
        int t = tt + eg;
        int tc = t < dg ? t : 0;         // dg >= 1 (self-loop)
        float p = t < dg ? pbuf[w][tc] : 0.f;
        int j = nbrs[w][tc];
        f32x4 wv = *(const f32x4*)(wrow + (size_t)j * NCPAD);
        acc += wv * splat4(p);
    }
    acc.x += __shfl_xor(acc.x, 32);
    acc.y += __shfl_xor(acc.y, 32);
    acc.z += __shfl_xor(acc.z, 32);
    acc.w += __shfl_xor(acc.w, 32);
    if (eg == 0) {
        int c4 = c * 4;
#pragma unroll
        for (int q = 0; q < 4; q++)
            if (c4 + q < NCLASS) out[(size_t)i * NCLASS + c4 + q] = acc[q] / s;
    }
}

// ---------------------------------------------------------------------------

extern "C" void kernel_launch(void* const* d_in, const int* in_sizes, int n_in,
                              void* d_out, int out_size, void* d_ws, size_t ws_size,
                              hipStream_t stream) {
    const float* x       = (const float*)d_in[0];  // [8192,256]
    const float* adj     = (const float*)d_in[1];  // [8192,8192]
    const float* Ws      = (const float*)d_in[2];  // [4,256,64]
    const float* a_heads = (const float*)d_in[3];  // [4,128]
    const float* Wout    = (const float*)d_in[4];  // [256,121]
    const float* aout    = (const float*)d_in[5];  // [242]
    float* out = (float*)d_out;                    // [8192,121]

    char* ws = (char*)d_ws;
    size_t off = 0;
    auto alloc = [&](size_t bytes) { void* p = ws + off; off = (off + bytes + 255) & ~(size_t)255; return p; };
    int*   nbr  = (int*)  alloc((size_t)N_NODES * CAP * 4);            // 8 MB
    int*   deg  = (int*)  alloc((size_t)N_NODES * 4);                  // 32 KB
    float* Wh1  = (float*)alloc((size_t)N_NODES * NHEADS * NHID * 4);  // 8 MB, interleaved rows
    float* fs1t = (float*)alloc((size_t)N_NODES * 4 * 4);              // 128 KB, node-major float4
    float* fd1t = (float*)alloc((size_t)N_NODES * 4 * 4);              // 128 KB
    float* hcat = (float*)alloc((size_t)N_NODES * NHEADS * NHID * 4);  // 8 MB
    float* Wh2  = (float*)alloc((size_t)N_NODES * NCPAD * 4);          // 4 MB
    float* fs2  = (float*)alloc((size_t)N_NODES * 4);
    float* fd2  = (float*)alloc((size_t)N_NODES * 4);
    float* Wpad = (float*)alloc((size_t)256 * NCPAD * 4);
    float* apad = (float*)alloc((size_t)256 * 4);

    build_csr<<<N_NODES, 256, 0, stream>>>(adj, nbr, deg);
    pad_params<<<128, 256, 0, stream>>>(Wout, aout, Wpad, apad);
    gemm1<<<dim3(N_NODES / 64, NHEADS), 256, 0, stream>>>(x, Ws, Wh1);
    attn_coef1<<<N_NODES, 256, 0, stream>>>(Wh1, a_heads, fs1t, fd1t);
    attn_agg1<<<N_NODES / 4, 256, 0, stream>>>(nbr, deg, Wh1, fs1t, fd1t, hcat);
    gemm2<<<N_NODES / 64, 256, 0, stream>>>(hcat, Wpad, Wh2);
    attn_coef2<<<N_NODES / 4, 256, 0, stream>>>(Wh2, apad, fs2, fd2);
    attn_agg2<<<N_NODES / 4, 256, 0, stream>>>(nbr, deg, Wh2, fs2, fd2, out);
}